// Round 5
// baseline (162.004 us; speedup 1.0000x reference)
//
#include <hip/hip_runtime.h>
#include <hip/hip_bf16.h>

#define NB 4
#define NC 128
#define NT 64
#define NHW 1024
#define KCH 128            // fp32 k-elements per chunk  -> 512 B burst per row
#define NCH (NHW / KCH)    // 8 chunks

typedef __attribute__((ext_vector_type(8))) short short8_t;
typedef __attribute__((ext_vector_type(4))) float float4_t;
typedef const unsigned __attribute__((address_space(1)))* gas_t;
typedef unsigned __attribute__((address_space(3)))* las_t;

// Split 8 fp32 (two float4) into bf16 hi/lo fragments (v = hi + lo, RNE).
__device__ __forceinline__ void cvt8(const float4& a, const float4& b,
                                     short8_t& h, short8_t& l) {
    const float vv[8] = {a.x, a.y, a.z, a.w, b.x, b.y, b.z, b.w};
    #pragma unroll
    for (int j = 0; j < 8; ++j) {
        __hip_bfloat16 hb = __float2bfloat16(vv[j]);
        float hf = __bfloat162float(hb);
        __hip_bfloat16 lb = __float2bfloat16(vv[j] - hf);
        h[j] = __builtin_bit_cast(short, hb);
        l[j] = __builtin_bit_cast(short, lb);
    }
}

// ---------------------------------------------------------------------------
// Kernel 1: partial energy, long-burst pipeline.
// grid = NB*NC = 512; block bc: part[bc][t][s] = sum_k x[bc,t,k]*y[bc,s,k]
// (k = all 1024 hw).  E ≈ xh·yh + xh·yl + xl·yh (fp32 MFMA accum).
// Per chunk: stage 64 rows x 512 B of x and y (global_load_lds, 2 rows per
// 1KB instruction -> long DRAM bursts), double-buffered (128 KB LDS,
// 1 block/CU). Raw s_barrier + counted vmcnt(16): next chunk's 64 KB stays
// in flight across barriers (never drain to 0 mid-loop).
// LDS XOR swizzle both-sides (rule #21): physical 16B-unit = logical ^
// (row&7); inverse applied on the per-lane GLOBAL source, LDS dest linear.
// ---------------------------------------------------------------------------
__global__ __launch_bounds__(256, 1) void k_energy(
    const float* __restrict__ x, const float* __restrict__ y,
    float* __restrict__ part)
{
    __shared__ float4 Xs[2][NT][32];   // 64 KB
    __shared__ float4 Ys[2][NT][32];   // 64 KB
    const int bc = blockIdx.x;
    const float* xb = x + (size_t)bc * NT * NHW;
    const float* yb = y + (size_t)bc * NT * NHW;
    const int lane = threadIdx.x & 63, w = threadIdx.x >> 6;
    const int r = lane & 15, g = lane >> 4;

    // staging: issue i stages rows {16w+2i, 16w+2i+1}; lane -> (rowhalf, unit)
    const int sh = lane >> 5;          // 0..1 row within pair
    const int su = lane & 31;          // dest 16B unit 0..31

    #define STAGE(pbuf, ch)                                                   \
        _Pragma("unroll")                                                     \
        for (int i = 0; i < 8; ++i) {                                         \
            const int row = 16 * w + 2 * i + sh;                              \
            const int uu  = su ^ (row & 7);                                   \
            __builtin_amdgcn_global_load_lds(                                 \
                (gas_t)(xb + (size_t)row * NHW + (ch) * KCH + uu * 4),        \
                (las_t)&Xs[pbuf][16 * w + 2 * i][0], 16, 0, 0);               \
            __builtin_amdgcn_global_load_lds(                                 \
                (gas_t)(yb + (size_t)row * NHW + (ch) * KCH + uu * 4),        \
                (las_t)&Ys[pbuf][16 * w + 2 * i][0], 16, 0, 0);               \
        }

    float4_t acc[4];
    #pragma unroll
    for (int ct = 0; ct < 4; ++ct)
        #pragma unroll
        for (int j = 0; j < 4; ++j) acc[ct][j] = 0.f;

    STAGE(0, 0);                       // 16 loads/wave in flight
    STAGE(1, 1);                       // 32 loads/wave in flight

    const int rx = r & 7;              // (16w+r)&7 == (16ct+r)&7 == r&7

    #pragma unroll
    for (int ch = 0; ch < NCH; ++ch) {
        const int pbuf = ch & 1;
        // wait for THIS chunk's 16 loads; keep the next 16 in flight
        if (ch < NCH - 1) {
            asm volatile("s_waitcnt vmcnt(16)" ::: "memory");
        } else {
            asm volatile("s_waitcnt vmcnt(0)" ::: "memory");
        }
        __builtin_amdgcn_sched_barrier(0);
        __builtin_amdgcn_s_barrier();  // all waves' chunk data now in LDS

        #pragma unroll
        for (int kk = 0; kk < 4; ++kk) {
            const int u0 = (kk * 8 + 2 * g) ^ rx;
            const int u1 = u0 ^ 1;     // (u even) ^ rx then +1 in logical
            short8_t ah, al;
            cvt8(Xs[pbuf][16 * w + r][u0], Xs[pbuf][16 * w + r][u1], ah, al);
            #pragma unroll
            for (int ct = 0; ct < 4; ++ct) {
                short8_t bh, bl;
                cvt8(Ys[pbuf][16 * ct + r][u0], Ys[pbuf][16 * ct + r][u1], bh, bl);
                acc[ct] = __builtin_amdgcn_mfma_f32_16x16x32_bf16(ah, bh, acc[ct], 0, 0, 0);
                acc[ct] = __builtin_amdgcn_mfma_f32_16x16x32_bf16(ah, bl, acc[ct], 0, 0, 0);
                acc[ct] = __builtin_amdgcn_mfma_f32_16x16x32_bf16(al, bh, acc[ct], 0, 0, 0);
            }
        }

        __builtin_amdgcn_sched_barrier(0);
        __builtin_amdgcn_s_barrier();  // all waves done reading this buffer
        if (ch + 2 < NCH) STAGE(pbuf, ch + 2);   // refill the freed buffer
    }
    #undef STAGE

    // C/D layout (m89-verified): col = lane&15, row = (lane>>4)*4 + reg
    float* pb_out = part + (size_t)bc * (NT * NT);
    #pragma unroll
    for (int ct = 0; ct < 4; ++ct)
        #pragma unroll
        for (int reg = 0; reg < 4; ++reg)
            pb_out[(16 * w + g * 4 + reg) * NT + 16 * ct + r] = acc[ct][reg];
}

// ---------------------------------------------------------------------------
// Kernel 2: reduce 128 partials per (b,t,s), row-softmax of (rowmax - e).
// grid = NB*NT blocks x 256 threads (4 slices); LDS reduce; wave 0 softmax.
// softmax(max-e) stabilized: p_s = exp(min_e - e_s), normalize.
// ---------------------------------------------------------------------------
__global__ void k_softmax(const float* __restrict__ part, float* __restrict__ att)
{
    const int b = blockIdx.x >> 6;
    const int t = blockIdx.x & 63;
    const int s = threadIdx.x & 63;
    const int sl = threadIdx.x >> 6;   // 0..3
    __shared__ float red[4][64];

    const float* p = part + (size_t)b * NC * (NT * NT) + t * NT + s;
    float e = 0.f;
    #pragma unroll 8
    for (int k = sl; k < NC; k += 4)
        e += p[(size_t)k * (NT * NT)];
    red[sl][s] = e;
    __syncthreads();
    if (threadIdx.x < 64) {
        e = red[0][s] + red[1][s] + red[2][s] + red[3][s];
        float mn = e;
        #pragma unroll
        for (int off = 32; off; off >>= 1) mn = fminf(mn, __shfl_xor(mn, off));
        float pv = expf(mn - e);
        float sum = pv;
        #pragma unroll
        for (int off = 32; off; off >>= 1) sum += __shfl_xor(sum, off);
        att[(size_t)blockIdx.x * NT + s] = pv / sum;
    }
}

// ---------------------------------------------------------------------------
// Kernel 3: out[b,c,t,hw] = x[b,c,t,hw] + scale * sum_s A[b,t,s]*y[b,c,s,hw]
// (unchanged — long 512 B bursts, ~6+ TB/s effective, near floor)
// ---------------------------------------------------------------------------
#define K3_SY 132
#define K3_SA 68
__global__ __launch_bounds__(256, 3) void k_out(
    const float* __restrict__ x, const float* __restrict__ y,
    const float* __restrict__ att, const float* __restrict__ scale_p,
    float* __restrict__ out)
{
    __shared__ float As[NT][K3_SA];   // As[s][t]
    __shared__ float Ys[NT][K3_SY];
    const int bc   = blockIdx.x >> 1;
    const int half = blockIdx.x & 1;
    const int b    = bc >> 7;
    const float scale = scale_p[0];
    const float* xb = x + (size_t)bc * NT * NHW + half * 512;
    const float* yb = y + (size_t)bc * NT * NHW + half * 512;
    float*       ob = out + (size_t)bc * NT * NHW + half * 512;
    const int tid = threadIdx.x;

    #pragma unroll
    for (int it = 0; it < 16; ++it) {
        int f = tid + it * 256;
        int t = f >> 6, s = f & 63;
        As[s][t] = att[((size_t)b * NT + t) * NT + s];
    }

    const int col = (tid & 31) * 4;
    const int g   = tid >> 5;

    for (int ch = 0; ch < 4; ++ch) {
        __syncthreads();
        #pragma unroll
        for (int it = 0; it < 8; ++it) {
            int f   = tid + it * 256;
            int row = f >> 5;
            int c4  = f & 31;
            *(float4*)(&Ys[row][c4 * 4]) =
                *(const float4*)(yb + (size_t)row * NHW + ch * 128 + c4 * 4);
        }
        __syncthreads();

        float4 acc[8] = {};
        #pragma unroll 4
        for (int s = 0; s < NT; ++s) {
            float4 yv = *(const float4*)(&Ys[s][col]);
            float4 al = *(const float4*)(&As[s][8 * g]);
            float4 ah = *(const float4*)(&As[s][8 * g + 4]);
            #define FMA4(A, S) \
                A.x = fmaf(S, yv.x, A.x); A.y = fmaf(S, yv.y, A.y); \
                A.z = fmaf(S, yv.z, A.z); A.w = fmaf(S, yv.w, A.w);
            FMA4(acc[0], al.x) FMA4(acc[1], al.y)
            FMA4(acc[2], al.z) FMA4(acc[3], al.w)
            FMA4(acc[4], ah.x) FMA4(acc[5], ah.y)
            FMA4(acc[6], ah.z) FMA4(acc[7], ah.w)
            #undef FMA4
        }

        #pragma unroll
        for (int rr = 0; rr < 8; ++rr) {
            int t = 8 * g + rr;
            float4 xv = *(const float4*)(xb + (size_t)t * NHW + ch * 128 + col);
            float4 o;
            o.x = fmaf(scale, acc[rr].x, xv.x);
            o.y = fmaf(scale, acc[rr].y, xv.y);
            o.z = fmaf(scale, acc[rr].z, xv.z);
            o.w = fmaf(scale, acc[rr].w, xv.w);
            *(float4*)(ob + (size_t)t * NHW + ch * 128 + col) = o;
        }
    }
}

// ---------------------------------------------------------------------------
extern "C" void kernel_launch(void* const* d_in, const int* in_sizes, int n_in,
                              void* d_out, int out_size, void* d_ws, size_t ws_size,
                              hipStream_t stream)
{
    const float* x       = (const float*)d_in[0];
    const float* y       = (const float*)d_in[1];
    const float* scale_p = (const float*)d_in[2];
    float* out = (float*)d_out;

    // Scratch: energy partials (512 x 64 x 64 fp32 = 8.4 MB) live in d_out,
    // fully overwritten by k_out afterwards; attention (64 KB) lives in d_ws.
    float* part = out;
    float* att  = (float*)d_ws;

    k_energy <<<dim3(NB * NC),     256, 0, stream>>>(x, y, part);
    k_softmax<<<dim3(NB * NT),     256, 0, stream>>>(part, att);
    k_out    <<<dim3(NB * NC * 2), 256, 0, stream>>>(x, y, att, scale_p, out);
}

// Round 6
// 141.716 us; speedup vs baseline: 1.1432x; 1.1432x over previous
//
#include <hip/hip_runtime.h>
#include <hip/hip_bf16.h>

#define NB 4
#define NC 128
#define NT 64
#define NHW 1024
#define KCH 128            // fp32 k-elements per chunk
#define NCH (NHW / KCH)    // 8 chunks
#define XSTR 136           // LDS row stride in shorts (128 + 8 pad, 272 B)

typedef __attribute__((ext_vector_type(8))) short short8_t;
typedef __attribute__((ext_vector_type(4))) short short4_t;
typedef __attribute__((ext_vector_type(4))) float float4_t;

// float4 -> 4 bf16 (RNE via __float2bfloat16; compiler emits cvt_pk pairs)
__device__ __forceinline__ short4_t cvt4(const float4& v) {
    short4_t o;
    o[0] = __builtin_bit_cast(short, __float2bfloat16(v.x));
    o[1] = __builtin_bit_cast(short, __float2bfloat16(v.y));
    o[2] = __builtin_bit_cast(short, __float2bfloat16(v.z));
    o[3] = __builtin_bit_cast(short, __float2bfloat16(v.w));
    return o;
}

// ---------------------------------------------------------------------------
// Kernel 1: partial energy — k_out-shaped staging + MFMA core.
// grid = NB*NC = 512; block bc: part[bc][t][s] = sum_k x[bc,t,k]*y[bc,s,k].
// Per chunk: each thread issues 16 LANE-CONTIGUOUS float4 loads (f=tid+256*it
// -> row=f>>5, unit=f&31; lane i reads base+16i — TA coalescer fast path,
// exactly k_out's pattern), converts to bf16 in-register, ds_writes to a
// padded LDS tile (stride 136 shorts: staging writes and fragment reads both
// conflict-floor). Next chunk's loads are issued BEFORE the MFMA phase (T14).
// Single bf16 (no hi/lo): softmax path stays finite; 16 MFMA/wave/chunk.
// ---------------------------------------------------------------------------
__global__ __launch_bounds__(256, 3) void k_energy(
    const float* __restrict__ x, const float* __restrict__ y,
    float* __restrict__ part)
{
    __shared__ __align__(16) short Xs[NT * XSTR];   // 17 KB
    __shared__ __align__(16) short Ys[NT * XSTR];   // 17 KB
    const int bc = blockIdx.x;
    const float* xb = x + (size_t)bc * NT * NHW;
    const float* yb = y + (size_t)bc * NT * NHW;
    const int tid = threadIdx.x;
    const int lane = tid & 63, w = tid >> 6;
    const int r = lane & 15, g = lane >> 4;

    float4 px[8], py[8];
    #pragma unroll
    for (int it = 0; it < 8; ++it) {               // chunk 0, lane-contiguous
        const int f = tid + it * 256;
        px[it] = *(const float4*)(xb + (size_t)(f >> 5) * NHW + (f & 31) * 4);
        py[it] = *(const float4*)(yb + (size_t)(f >> 5) * NHW + (f & 31) * 4);
    }

    float4_t acc[4];
    #pragma unroll
    for (int ct = 0; ct < 4; ++ct)
        #pragma unroll
        for (int j = 0; j < 4; ++j) acc[ct][j] = 0.f;

    for (int ch = 0; ch < NCH; ++ch) {
        __syncthreads();                           // LDS free (prev compute done)
        #pragma unroll
        for (int it = 0; it < 8; ++it) {
            const int f = tid + it * 256;
            const int row = f >> 5, u = f & 31;
            *(short4_t*)(&Xs[row * XSTR + u * 4]) = cvt4(px[it]);
            *(short4_t*)(&Ys[row * XSTR + u * 4]) = cvt4(py[it]);
        }
        __syncthreads();                           // tile ready
        if (ch + 1 < NCH) {                        // prefetch under MFMA phase
            const int ko = (ch + 1) * KCH;
            #pragma unroll
            for (int it = 0; it < 8; ++it) {
                const int f = tid + it * 256;
                px[it] = *(const float4*)(xb + (size_t)(f >> 5) * NHW + ko + (f & 31) * 4);
                py[it] = *(const float4*)(yb + (size_t)(f >> 5) * NHW + ko + (f & 31) * 4);
            }
        }
        #pragma unroll
        for (int kk = 0; kk < 4; ++kk) {
            const short8_t a = *(const short8_t*)(&Xs[(16 * w + r) * XSTR + kk * 32 + g * 8]);
            #pragma unroll
            for (int ct = 0; ct < 4; ++ct) {
                const short8_t b = *(const short8_t*)(&Ys[(16 * ct + r) * XSTR + kk * 32 + g * 8]);
                acc[ct] = __builtin_amdgcn_mfma_f32_16x16x32_bf16(a, b, acc[ct], 0, 0, 0);
            }
        }
    }

    // C/D layout (m89-verified): col = lane&15, row = (lane>>4)*4 + reg
    float* pb_out = part + (size_t)bc * (NT * NT);
    #pragma unroll
    for (int ct = 0; ct < 4; ++ct)
        #pragma unroll
        for (int reg = 0; reg < 4; ++reg)
            pb_out[(16 * w + g * 4 + reg) * NT + 16 * ct + r] = acc[ct][reg];
}

// ---------------------------------------------------------------------------
// Kernel 2: reduce 128 partials per (b,t,s), row-softmax of (rowmax - e).
// grid = NB*NT blocks x 256 threads (4 slices); LDS reduce; wave 0 softmax.
// softmax(max-e) stabilized: p_s = exp(min_e - e_s), normalize.
// ---------------------------------------------------------------------------
__global__ void k_softmax(const float* __restrict__ part, float* __restrict__ att)
{
    const int b = blockIdx.x >> 6;
    const int t = blockIdx.x & 63;
    const int s = threadIdx.x & 63;
    const int sl = threadIdx.x >> 6;   // 0..3
    __shared__ float red[4][64];

    const float* p = part + (size_t)b * NC * (NT * NT) + t * NT + s;
    float e = 0.f;
    #pragma unroll 8
    for (int k = sl; k < NC; k += 4)
        e += p[(size_t)k * (NT * NT)];
    red[sl][s] = e;
    __syncthreads();
    if (threadIdx.x < 64) {
        e = red[0][s] + red[1][s] + red[2][s] + red[3][s];
        float mn = e;
        #pragma unroll
        for (int off = 32; off; off >>= 1) mn = fminf(mn, __shfl_xor(mn, off));
        float pv = expf(mn - e);
        float sum = pv;
        #pragma unroll
        for (int off = 32; off; off >>= 1) sum += __shfl_xor(sum, off);
        att[(size_t)blockIdx.x * NT + s] = pv / sum;
    }
}

// ---------------------------------------------------------------------------
// Kernel 3: out[b,c,t,hw] = x[b,c,t,hw] + scale * sum_s A[b,t,s]*y[b,c,s,hw]
// (unchanged — the fast template this round's k_energy copies)
// ---------------------------------------------------------------------------
#define K3_SY 132
#define K3_SA 68
__global__ __launch_bounds__(256, 3) void k_out(
    const float* __restrict__ x, const float* __restrict__ y,
    const float* __restrict__ att, const float* __restrict__ scale_p,
    float* __restrict__ out)
{
    __shared__ float As[NT][K3_SA];   // As[s][t]
    __shared__ float Ys[NT][K3_SY];
    const int bc   = blockIdx.x >> 1;
    const int half = blockIdx.x & 1;
    const int b    = bc >> 7;
    const float scale = scale_p[0];
    const float* xb = x + (size_t)bc * NT * NHW + half * 512;
    const float* yb = y + (size_t)bc * NT * NHW + half * 512;
    float*       ob = out + (size_t)bc * NT * NHW + half * 512;
    const int tid = threadIdx.x;

    #pragma unroll
    for (int it = 0; it < 16; ++it) {
        int f = tid + it * 256;
        int t = f >> 6, s = f & 63;
        As[s][t] = att[((size_t)b * NT + t) * NT + s];
    }

    const int col = (tid & 31) * 4;
    const int g   = tid >> 5;

    for (int ch = 0; ch < 4; ++ch) {
        __syncthreads();
        #pragma unroll
        for (int it = 0; it < 8; ++it) {
            int f   = tid + it * 256;
            int row = f >> 5;
            int c4  = f & 31;
            *(float4*)(&Ys[row][c4 * 4]) =
                *(const float4*)(yb + (size_t)row * NHW + ch * 128 + c4 * 4);
        }
        __syncthreads();

        float4 acc[8] = {};
        #pragma unroll 4
        for (int s = 0; s < NT; ++s) {
            float4 yv = *(const float4*)(&Ys[s][col]);
            float4 al = *(const float4*)(&As[s][8 * g]);
            float4 ah = *(const float4*)(&As[s][8 * g + 4]);
            #define FMA4(A, S) \
                A.x = fmaf(S, yv.x, A.x); A.y = fmaf(S, yv.y, A.y); \
                A.z = fmaf(S, yv.z, A.z); A.w = fmaf(S, yv.w, A.w);
            FMA4(acc[0], al.x) FMA4(acc[1], al.y)
            FMA4(acc[2], al.z) FMA4(acc[3], al.w)
            FMA4(acc[4], ah.x) FMA4(acc[5], ah.y)
            FMA4(acc[6], ah.z) FMA4(acc[7], ah.w)
            #undef FMA4
        }

        #pragma unroll
        for (int rr = 0; rr < 8; ++rr) {
            int t = 8 * g + rr;
            float4 xv = *(const float4*)(xb + (size_t)t * NHW + ch * 128 + col);
            float4 o;
            o.x = fmaf(scale, acc[rr].x, xv.x);
            o.y = fmaf(scale, acc[rr].y, xv.y);
            o.z = fmaf(scale, acc[rr].z, xv.z);
            o.w = fmaf(scale, acc[rr].w, xv.w);
            *(float4*)(ob + (size_t)t * NHW + ch * 128 + col) = o;
        }
    }
}

// ---------------------------------------------------------------------------
extern "C" void kernel_launch(void* const* d_in, const int* in_sizes, int n_in,
                              void* d_out, int out_size, void* d_ws, size_t ws_size,
                              hipStream_t stream)
{
    const float* x       = (const float*)d_in[0];
    const float* y       = (const float*)d_in[1];
    const float* scale_p = (const float*)d_in[2];
    float* out = (float*)d_out;

    // Scratch: energy partials (512 x 64 x 64 fp32 = 8.4 MB) live in d_out,
    // fully overwritten by k_out afterwards; attention (64 KB) lives in d_ws.
    float* part = out;
    float* att  = (float*)d_ws;

    k_energy <<<dim3(NB * NC),     256, 0, stream>>>(x, y, part);
    k_softmax<<<dim3(NB * NT),     256, 0, stream>>>(part, att);
    k_out    <<<dim3(NB * NC * 2), 256, 0, stream>>>(x, y, att, scale_p, out);
}